// Round 12
// baseline (79.477 us; speedup 1.0000x reference)
//
#include <hip/hip_runtime.h>
#include <hip/hip_bf16.h>

// B=8, T=2048, C=1024, H=64.  ref: wei=(k q^T)/32 causal, softmax over s, @v.
// R12: barrier-free proj. BM=16, 1024 blocks x 4 waves; each wave fully
// independent: A-frags direct from x (f32->bf16 in reg, row=c/chunk=g lane
// pattern: 4 lanes share one 128B line -> 100% utilization), B-frags from
// L2-resident wfrag. Main loop has ZERO LDS / ZERO barriers; 8KB LDS epilogue
// (one barrier) emits frag-major K/Q/V (two ssub-blocks per 32-row tile).
// attn (in-block split + LDS merge) and wcvt unchanged from R11.

typedef __attribute__((ext_vector_type(8))) short short8;   // 8 bf16
typedef __attribute__((ext_vector_type(4))) float f32x4;
typedef __attribute__((ext_vector_type(16))) float f32x16;
typedef unsigned int u32;

#define BATCH 8
#define T 2048
#define CDIM 1024
#define HD 64
#define QK_SCALE 0.04508422f      // log2(e)/32  (exp2-domain softmax)

static __device__ __forceinline__ short f2bf(float f) {
    return __builtin_bit_cast(short, __float2bfloat16(f));   // RNE
}
static __device__ __forceinline__ float bf2f(unsigned short s) {
    u32 u = ((u32)s) << 16;
    return __builtin_bit_cast(float, u);
}
static __device__ __forceinline__ u32 packbf(float lo, float hi) {
    return (u32)(unsigned short)f2bf(lo) | ((u32)(unsigned short)f2bf(hi) << 16);
}
static __device__ __forceinline__ f32x4 mfma16(short8 a, short8 b, f32x4 c) {
    return __builtin_amdgcn_mfma_f32_16x16x32_bf16(a, b, c, 0, 0, 0);
}
static __device__ __forceinline__ f32x16 mfma32(short8 a, short8 b, f32x16 c) {
    return __builtin_amdgcn_mfma_f32_32x32x16_bf16(a, b, c, 0, 0, 0);
}

// ---------------- W -> frag-major bf16 (unchanged) ----------------
__global__ __launch_bounds__(256) void wcvt_kernel(
    const float* __restrict__ Wk, const float* __restrict__ Wq,
    const float* __restrict__ Wv, short* __restrict__ wfrag)
{
    const int t = blockIdx.x * 256 + threadIdx.x;   // 0..24575
    const int lane = t & 63, kk = (t >> 6) & 31, d16 = (t >> 11) & 3, p = t >> 13;
    const float* __restrict__ W = (p == 0) ? Wk : (p == 1 ? Wq : Wv);
    const float sc = (p == 0) ? QK_SCALE : 1.0f;
    const float* src = W + (size_t)(d16 * 16 + (lane & 15)) * CDIM
                         + kk * 32 + ((lane >> 4) & 3) * 8;
    f32x4 a = *(const f32x4*)src;
    f32x4 b = *(const f32x4*)(src + 4);
    short8 o;
#pragma unroll
    for (int e = 0; e < 4; ++e) { o[e] = f2bf(a[e] * sc); o[e + 4] = f2bf(b[e] * sc); }
    *(short8*)(wfrag + (size_t)t * 8) = o;
}

// ---------------- projection v4: barrier-free, BM=16 ----------------
// 1024 blocks x 256 thr. Wave wid = cg (48 of 192 output cols), full K.
// A-frag: lane holds x[row0 + c][kk*32 + g*8 .. +8] (f32 loads + cvt).
__global__ __launch_bounds__(256) void proj_kernel(
    const float* __restrict__ x, const short* __restrict__ wfrag,
    short* __restrict__ kfrag, short* __restrict__ qfrag, short* __restrict__ vfrag)
{
    __shared__ __align__(16) short st_k[16 * 72];   // [row][d]
    __shared__ __align__(16) short st_q[16 * 72];
    __shared__ __align__(16) short st_v[64 * 24];   // [d][row] (transposed)

    const int tid = threadIdx.x, cg = tid >> 6, lane = tid & 63;
    const int c = lane & 15, g = lane >> 4;
    const int row0 = blockIdx.x * 16;
    const float* __restrict__ xr = x + (size_t)(row0 + c) * CDIM + g * 8;

    f32x4 acc[3] = {};
#pragma unroll 4
    for (int kk = 0; kk < 32; ++kk) {
        const float* ax = xr + kk * 32;
        f32x4 a0 = *(const f32x4*)ax;
        f32x4 a1 = *(const f32x4*)(ax + 4);
        short8 af = { f2bf(a0[0]), f2bf(a0[1]), f2bf(a0[2]), f2bf(a0[3]),
                      f2bf(a1[0]), f2bf(a1[1]), f2bf(a1[2]), f2bf(a1[3]) };
#pragma unroll
        for (int j = 0; j < 3; ++j) {
            const int q = cg * 3 + j;
            short8 bf = *(const short8*)&wfrag[(size_t)(q * 32 + kk) * 512 + lane * 8];
            acc[j] = mfma16(af, bf, acc[j]);
        }
    }

    // ---- stage through LDS (one barrier), emit frag-major ----
#pragma unroll
    for (int j = 0; j < 3; ++j) {
        const int q = cg * 3 + j, p = q >> 2, d16 = q & 3;
#pragma unroll
        for (int r = 0; r < 4; ++r) {
            const int row = g * 4 + r;                 // 0..15
            const short v = f2bf(acc[j][r]);
            if (p == 0)      st_k[row * 72 + d16 * 16 + c] = v;
            else if (p == 1) st_q[row * 72 + d16 * 16 + c] = v;
            else             st_v[(d16 * 16 + c) * 24 + row] = v;
        }
    }
    __syncthreads();

    const int b = row0 >> 11, i = (row0 & 2047) >> 5, ssub = (row0 >> 4) & 1;
    const size_t tb = ((size_t)(b * 64 + i)) * 4;
    const int l5 = lane & 31, h = lane >> 5;
    const int ks = cg;                                  // frag slot 0..3

    if ((l5 >> 4) == ssub) {                            // our 16 tile-rows
        const int rl = l5 & 15;
        short8 kv = *(short8*)&st_k[rl * 72 + ks * 16 + h * 8];
        *(short8*)&kfrag[(tb + ks) * 512 + lane * 8] = kv;
        short8 qv = *(short8*)&st_q[rl * 72 + ks * 16 + h * 8];
        *(short8*)&qfrag[(tb + ks) * 512 + lane * 8] = qv;
    }
    if (cg < 2) {                                       // V frags (dh, ssub)
        const int dh = cg;
        short8 vv = *(short8*)&st_v[(dh * 32 + l5) * 24 + h * 8];
        *(short8*)&vfrag[(tb + dh * 2 + ssub) * 512 + lane * 8] = vv;
    }
}

// ---------------- attention: in-block 8-way split-s + LDS merge (R11) -------
__global__ __launch_bounds__(512) void attn_kernel(
    const short* __restrict__ kfrag, const short* __restrict__ qfrag,
    const short* __restrict__ vfrag, float* __restrict__ out)
{
    const int tid = threadIdx.x, wid = tid >> 6, lane = tid & 63;
    const int l5 = lane & 31, h = lane >> 5;
    const int bx = blockIdx.x;
    const int i = 63 - (bx >> 3);            // big tiles dispatch first
    const int b = bx & 7;                    // XCD round-robin over batches
    const int t0 = i * 32;

    __shared__ u32   sO[8][32][32];          // [wave][dpair][t] bf16-pairs, 32KB
    __shared__ float sML[8][2][32];          // [wave][{m,l}][t], 2KB

    const short* __restrict__ kb = kfrag + ((size_t)(b * 64 + i)) * 2048;
    const short* __restrict__ qb = qfrag + ((size_t)b * 64) * 2048;
    const short* __restrict__ vb = vfrag + ((size_t)b * 64) * 2048;

    short8 kf[4];
#pragma unroll
    for (int ks = 0; ks < 4; ++ks)
        kf[ks] = *(const short8*)&kb[ks * 512 + lane * 8];

    float m = -1e30f, l = 0.f;
    f32x16 o0 = {}, o1 = {};                 // O^T: rows=d (regs), col=t (lane)

    short8 qf[4], vf[4], qn[4], vn[4];
#pragma unroll
    for (int ks = 0; ks < 4; ++ks) {         // st=wid <= 7 is always valid
        qf[ks] = *(const short8*)&qb[((size_t)wid * 4 + ks) * 512 + lane * 8];
        vf[ks] = *(const short8*)&vb[((size_t)wid * 4 + ks) * 512 + lane * 8];
    }

    for (int st = wid; st <= i; st += 8) {
        f32x16 Cs = {};
#pragma unroll
        for (int ks = 0; ks < 4; ++ks)
            Cs = mfma32(qf[ks], kf[ks], Cs);

        if (st + 8 <= i) {                   // prefetch next step
#pragma unroll
            for (int ks = 0; ks < 4; ++ks) {
                qn[ks] = *(const short8*)&qb[((size_t)(st + 8) * 4 + ks) * 512 + lane * 8];
                vn[ks] = *(const short8*)&vb[((size_t)(st + 8) * 4 + ks) * 512 + lane * 8];
            }
        }

        if (st == i) {                       // diagonal tile: mask s > t
#pragma unroll
            for (int r = 0; r < 16; ++r) {
                const int srow = (r & 3) + 8 * (r >> 2) + 4 * h;
                if (srow > l5) Cs[r] = -1e30f;
            }
        }
        float mx = fmaxf(Cs[0], Cs[1]);
#pragma unroll
        for (int r = 2; r < 16; ++r) mx = fmaxf(mx, Cs[r]);
        mx = fmaxf(mx, __shfl_xor(mx, 32));
        if (!__all(mx <= m)) {               // defer-rescale
            const float mnew = fmaxf(m, mx);
            const float alpha = exp2f(m - mnew);
            m = mnew;
            l *= alpha;
#pragma unroll
            for (int r = 0; r < 16; ++r) { o0[r] *= alpha; o1[r] *= alpha; }
        }
        u32 pk[8];
        float rs = 0.f;
#pragma unroll
        for (int q = 0; q < 8; ++q) {
            const float e0 = exp2f(Cs[2 * q] - m);
            const float e1 = exp2f(Cs[2 * q + 1] - m);
            rs += e0 + e1;
            pk[q] = packbf(e0, e1);
        }
        rs += __shfl_xor(rs, 32);
        l += rs;

        u32 w0 = pk[0], w2 = pk[2];
        asm volatile("v_permlane32_swap_b32 %0, %1" : "+v"(w0), "+v"(w2));
        u32 w1 = pk[1], w3 = pk[3];
        asm volatile("v_permlane32_swap_b32 %0, %1" : "+v"(w1), "+v"(w3));
        u32 w4 = pk[4], w6 = pk[6];
        asm volatile("v_permlane32_swap_b32 %0, %1" : "+v"(w4), "+v"(w6));
        u32 w5 = pk[5], w7 = pk[7];
        asm volatile("v_permlane32_swap_b32 %0, %1" : "+v"(w5), "+v"(w7));
        short8 pf0, pf1;
        pf0[0] = (short)(w0 & 0xffff); pf0[1] = (short)(w0 >> 16);
        pf0[2] = (short)(w1 & 0xffff); pf0[3] = (short)(w1 >> 16);
        pf0[4] = (short)(w2 & 0xffff); pf0[5] = (short)(w2 >> 16);
        pf0[6] = (short)(w3 & 0xffff); pf0[7] = (short)(w3 >> 16);
        pf1[0] = (short)(w4 & 0xffff); pf1[1] = (short)(w4 >> 16);
        pf1[2] = (short)(w5 & 0xffff); pf1[3] = (short)(w5 >> 16);
        pf1[4] = (short)(w6 & 0xffff); pf1[5] = (short)(w6 >> 16);
        pf1[6] = (short)(w7 & 0xffff); pf1[7] = (short)(w7 >> 16);

        o0 = mfma32(vf[0], pf0, o0);
        o0 = mfma32(vf[1], pf1, o0);
        o1 = mfma32(vf[2], pf0, o1);
        o1 = mfma32(vf[3], pf1, o1);

#pragma unroll
        for (int ks = 0; ks < 4; ++ks) { qf[ks] = qn[ks]; vf[ks] = vn[ks]; }
    }

    // ---- partial store to LDS ----
#pragma unroll
    for (int q = 0; q < 8; ++q) {
        const int dp = (q & 1) + 4 * (q >> 1) + 2 * h;
        sO[wid][dp][l5]      = packbf(o0[2 * q], o0[2 * q + 1]);
        sO[wid][16 + dp][l5] = packbf(o1[2 * q], o1[2 * q + 1]);
    }
    if (h == 0) { sML[wid][0][l5] = m; sML[wid][1][l5] = l; }
    __syncthreads();

    // ---- 8-way merge ----
    float M = -1e30f;
#pragma unroll
    for (int p = 0; p < 8; ++p) M = fmaxf(M, sML[p][0][l5]);
    float L = 0.f;
    float av[4] = {};
#pragma unroll
    for (int p = 0; p < 8; ++p) {
        const float w = exp2f(sML[p][0][l5] - M);
        L += w * sML[p][1][l5];
#pragma unroll
        for (int dd2 = 0; dd2 < 2; ++dd2) {
            const u32 v = sO[p][wid * 4 + h * 2 + dd2][l5];
            av[2 * dd2]     += w * bf2f((unsigned short)(v & 0xffff));
            av[2 * dd2 + 1] += w * bf2f((unsigned short)(v >> 16));
        }
    }
    const float inv = 1.f / L;
    f32x4 r = { av[0] * inv, av[1] * inv, av[2] * inv, av[3] * inv };
    *(f32x4*)&out[((size_t)b * T + t0 + l5) * HD + wid * 8 + h * 4] = r;
}

extern "C" void kernel_launch(void* const* d_in, const int* in_sizes, int n_in,
                              void* d_out, int out_size, void* d_ws, size_t ws_size,
                              hipStream_t stream) {
    const float* x  = (const float*)d_in[0];
    const float* Wk = (const float*)d_in[1];
    const float* Wq = (const float*)d_in[2];
    const float* Wv = (const float*)d_in[3];
    float* out = (float*)d_out;

    short* kfrag = (short*)d_ws;                        // [512 tiles][4][64][8]
    short* qfrag = kfrag + (size_t)BATCH * T * HD;
    short* vfrag = qfrag + (size_t)BATCH * T * HD;
    short* wfrag = vfrag + (size_t)BATCH * T * HD;      // [12][32][64][8]

    wcvt_kernel<<<96, 256, 0, stream>>>(Wk, Wq, Wv, wfrag);
    proj_kernel<<<1024, 256, 0, stream>>>(x, wfrag, kfrag, qfrag, vfrag);
    attn_kernel<<<512, 512, 0, stream>>>(kfrag, qfrag, vfrag, out);
}

// Round 13
// 42.641 us; speedup vs baseline: 1.8639x; 1.8639x over previous
//
#include <hip/hip_runtime.h>
#include <hip/hip_bf16.h>

// B=8, T=2048, C=1024, H=64.  ref: wei=(k q^T)/32 causal, softmax over s, @v.
// R13: proj v5 — register-prefetched W-frags (next chunk's 6 B-frags loaded
// to regs BEFORE current chunk's MFMAs -> L2 latency hidden under compute;
// reg loads survive s_barrier un-drained). BM=32, 512 blocks (2/CU), x staged
// bf16 in XOR-swizzled LDS dbuf. Epilogue = R9's verified frag-major emit.
// attn (in-block split + LDS merge) / wcvt unchanged from R11.

typedef __attribute__((ext_vector_type(8))) short short8;   // 8 bf16
typedef __attribute__((ext_vector_type(4))) float f32x4;
typedef __attribute__((ext_vector_type(16))) float f32x16;
typedef unsigned int u32;

#define BATCH 8
#define T 2048
#define CDIM 1024
#define HD 64
#define QK_SCALE 0.04508422f      // log2(e)/32  (exp2-domain softmax)

static __device__ __forceinline__ short f2bf(float f) {
    return __builtin_bit_cast(short, __float2bfloat16(f));   // RNE
}
static __device__ __forceinline__ float bf2f(unsigned short s) {
    u32 u = ((u32)s) << 16;
    return __builtin_bit_cast(float, u);
}
static __device__ __forceinline__ u32 packbf(float lo, float hi) {
    return (u32)(unsigned short)f2bf(lo) | ((u32)(unsigned short)f2bf(hi) << 16);
}
static __device__ __forceinline__ f32x4 mfma16(short8 a, short8 b, f32x4 c) {
    return __builtin_amdgcn_mfma_f32_16x16x32_bf16(a, b, c, 0, 0, 0);
}
static __device__ __forceinline__ f32x16 mfma32(short8 a, short8 b, f32x16 c) {
    return __builtin_amdgcn_mfma_f32_32x32x16_bf16(a, b, c, 0, 0, 0);
}

// ---------------- W -> frag-major bf16 (unchanged) ----------------
__global__ __launch_bounds__(256) void wcvt_kernel(
    const float* __restrict__ Wk, const float* __restrict__ Wq,
    const float* __restrict__ Wv, short* __restrict__ wfrag)
{
    const int t = blockIdx.x * 256 + threadIdx.x;   // 0..24575
    const int lane = t & 63, kk = (t >> 6) & 31, d16 = (t >> 11) & 3, p = t >> 13;
    const float* __restrict__ W = (p == 0) ? Wk : (p == 1 ? Wq : Wv);
    const float sc = (p == 0) ? QK_SCALE : 1.0f;
    const float* src = W + (size_t)(d16 * 16 + (lane & 15)) * CDIM
                         + kk * 32 + ((lane >> 4) & 3) * 8;
    f32x4 a = *(const f32x4*)src;
    f32x4 b = *(const f32x4*)(src + 4);
    short8 o;
#pragma unroll
    for (int e = 0; e < 4; ++e) { o[e] = f2bf(a[e] * sc); o[e + 4] = f2bf(b[e] * sc); }
    *(short8*)(wfrag + (size_t)t * 8) = o;
}

// ---------------- projection v5: BM=32, reg-prefetched B, swizzled x LDS ----
// 512 blocks x 256 thr (4 waves). Wave cg owns 3 output col-16-tiles
// (q = 3cg..3cg+2) x 32 rows (2 A-frags). 16 chunks of BK=64 k-floats.
#define XLOAD(KC) { \
    xr0 = *(const f32x4*)(xsrc + (KC) * 64); \
    xr1 = *(const f32x4*)(xsrc + (KC) * 64 + 4); }

#define XWRITE(BASE) { \
    short8 v = { f2bf(xr0[0]), f2bf(xr0[1]), f2bf(xr0[2]), f2bf(xr0[3]), \
                 f2bf(xr1[0]), f2bf(xr1[1]), f2bf(xr1[2]), f2bf(xr1[3]) }; \
    *(short8*)((BASE) + srow * 128 + ((sseg * 16) ^ ((srow & 7) << 4))) = v; }

#define BLOAD(DST, KC) \
    _Pragma("unroll") for (int u = 0; u < 6; ++u) \
        DST[u] = *(const short8*)&wfrag[(size_t)((cg * 3 + (u % 3)) * 32 + (KC) * 2 + (u / 3)) * 512 + lane * 8];

#define COMPUTE(XBASE, B) \
    _Pragma("unroll") for (int kkL = 0; kkL < 2; ++kkL) { \
        short8 af0 = *(short8*)((XBASE) + c * 128 + ((kkL * 64 + g * 16) ^ ((c & 7) << 4))); \
        short8 af1 = *(short8*)((XBASE) + (16 + c) * 128 + ((kkL * 64 + g * 16) ^ ((c & 7) << 4))); \
        _Pragma("unroll") for (int j = 0; j < 3; ++j) { \
            acc[0][j] = mfma16(af0, B[kkL * 3 + j], acc[0][j]); \
            acc[1][j] = mfma16(af1, B[kkL * 3 + j], acc[1][j]); } }

__global__ __launch_bounds__(256) void proj_kernel(
    const float* __restrict__ x, const short* __restrict__ wfrag,
    short* __restrict__ kfrag, short* __restrict__ qfrag, short* __restrict__ vfrag)
{
    __shared__ __align__(16) char lds[16384];
    char* X0 = lds;            // [32 rows][128B] bf16, XOR-swizzled
    char* X1 = lds + 4096;

    const int tid = threadIdx.x, cg = tid >> 6, lane = tid & 63;
    const int c = lane & 15, g = lane >> 4;
    const int srow = tid >> 3, sseg = tid & 7;
    const int row0 = blockIdx.x * 32;
    const float* __restrict__ xsrc = x + (size_t)(row0 + srow) * CDIM + sseg * 8;

    f32x4 acc[2][3] = {};
    short8 bA[6], bB[6];
    f32x4 xr0, xr1;

    // prologue: chunk 0 -> X0 / bA
    XLOAD(0)
    XWRITE(X0)
    BLOAD(bA, 0)
    __syncthreads();

    for (int c2 = 0; c2 < 8; ++c2) {
        const int cB = 2 * c2 + 1;
        // phase A: prefetch chunk cB, compute chunk 2*c2 from X0/bA
        BLOAD(bB, cB)
        XLOAD(cB)
        COMPUTE(X0, bA)
        XWRITE(X1)
        __syncthreads();
        // phase B: prefetch chunk cB+1, compute chunk cB from X1/bB
        if (c2 < 7) {
            BLOAD(bA, cB + 1)
            XLOAD(cB + 1)
        }
        COMPUTE(X1, bB)
        if (c2 < 7) {
            XWRITE(X0)
        }
        __syncthreads();
    }

    // ---- epilogue: stage frag-major through LDS (R9 layout, th=0) ----
    short* st_k = (short*)lds;              // [32 t][72]
    short* st_q = (short*)(lds + 4608);     // [32 t][72]
    short* st_v = (short*)(lds + 9216);     // [64 d][40] (transposed)
#pragma unroll
    for (int j = 0; j < 3; ++j) {
        const int q = cg * 3 + j, p = q >> 2, d16 = q & 3;
#pragma unroll
        for (int rh = 0; rh < 2; ++rh)
#pragma unroll
            for (int r = 0; r < 4; ++r) {
                const int mrow = rh * 16 + g * 4 + r;
                const short v = f2bf(acc[rh][j][r]);
                if (p == 0)      st_k[mrow * 72 + d16 * 16 + c] = v;
                else if (p == 1) st_q[mrow * 72 + d16 * 16 + c] = v;
                else             st_v[(d16 * 16 + c) * 40 + mrow] = v;
            }
    }
    __syncthreads();

    const int b = row0 >> 11, i = (row0 & 2047) >> 5;
    const size_t tb = ((size_t)(b * 64 + i)) * 4;
    const int l5 = lane & 31, h = lane >> 5;
    const int fq = cg;

    short8 kv = *(short8*)&st_k[l5 * 72 + fq * 16 + h * 8];
    *(short8*)&kfrag[(tb + fq) * 512 + lane * 8] = kv;
    short8 qv = *(short8*)&st_q[l5 * 72 + fq * 16 + h * 8];
    *(short8*)&qfrag[(tb + fq) * 512 + lane * 8] = qv;
    const int dh = fq >> 1, ssub = fq & 1;
    short8 vv = *(short8*)&st_v[(dh * 32 + l5) * 40 + ssub * 16 + h * 8];
    *(short8*)&vfrag[(tb + fq) * 512 + lane * 8] = vv;
}

// ---------------- attention: in-block 8-way split-s + LDS merge (R11) -------
__global__ __launch_bounds__(512) void attn_kernel(
    const short* __restrict__ kfrag, const short* __restrict__ qfrag,
    const short* __restrict__ vfrag, float* __restrict__ out)
{
    const int tid = threadIdx.x, wid = tid >> 6, lane = tid & 63;
    const int l5 = lane & 31, h = lane >> 5;
    const int bx = blockIdx.x;
    const int i = 63 - (bx >> 3);            // big tiles dispatch first
    const int b = bx & 7;                    // XCD round-robin over batches
    const int t0 = i * 32;

    __shared__ u32   sO[8][32][32];          // [wave][dpair][t] bf16-pairs, 32KB
    __shared__ float sML[8][2][32];          // [wave][{m,l}][t], 2KB

    const short* __restrict__ kb = kfrag + ((size_t)(b * 64 + i)) * 2048;
    const short* __restrict__ qb = qfrag + ((size_t)b * 64) * 2048;
    const short* __restrict__ vb = vfrag + ((size_t)b * 64) * 2048;

    short8 kf[4];
#pragma unroll
    for (int ks = 0; ks < 4; ++ks)
        kf[ks] = *(const short8*)&kb[ks * 512 + lane * 8];

    float m = -1e30f, l = 0.f;
    f32x16 o0 = {}, o1 = {};                 // O^T: rows=d (regs), col=t (lane)

    short8 qf[4], vf[4], qn[4], vn[4];
#pragma unroll
    for (int ks = 0; ks < 4; ++ks) {         // st=wid <= 7 is always valid
        qf[ks] = *(const short8*)&qb[((size_t)wid * 4 + ks) * 512 + lane * 8];
        vf[ks] = *(const short8*)&vb[((size_t)wid * 4 + ks) * 512 + lane * 8];
    }

    for (int st = wid; st <= i; st += 8) {
        f32x16 Cs = {};
#pragma unroll
        for (int ks = 0; ks < 4; ++ks)
            Cs = mfma32(qf[ks], kf[ks], Cs);

        if (st + 8 <= i) {                   // prefetch next step
#pragma unroll
            for (int ks = 0; ks < 4; ++ks) {
                qn[ks] = *(const short8*)&qb[((size_t)(st + 8) * 4 + ks) * 512 + lane * 8];
                vn[ks] = *(const short8*)&vb[((size_t)(st + 8) * 4 + ks) * 512 + lane * 8];
            }
        }

        if (st == i) {                       // diagonal tile: mask s > t
#pragma unroll
            for (int r = 0; r < 16; ++r) {
                const int srow = (r & 3) + 8 * (r >> 2) + 4 * h;
                if (srow > l5) Cs[r] = -1e30f;
            }
        }
        float mx = fmaxf(Cs[0], Cs[1]);
#pragma unroll
        for (int r = 2; r < 16; ++r) mx = fmaxf(mx, Cs[r]);
        mx = fmaxf(mx, __shfl_xor(mx, 32));
        if (!__all(mx <= m)) {               // defer-rescale
            const float mnew = fmaxf(m, mx);
            const float alpha = exp2f(m - mnew);
            m = mnew;
            l *= alpha;
#pragma unroll
            for (int r = 0; r < 16; ++r) { o0[r] *= alpha; o1[r] *= alpha; }
        }
        u32 pk[8];
        float rs = 0.f;
#pragma unroll
        for (int q = 0; q < 8; ++q) {
            const float e0 = exp2f(Cs[2 * q] - m);
            const float e1 = exp2f(Cs[2 * q + 1] - m);
            rs += e0 + e1;
            pk[q] = packbf(e0, e1);
        }
        rs += __shfl_xor(rs, 32);
        l += rs;

        u32 w0 = pk[0], w2 = pk[2];
        asm volatile("v_permlane32_swap_b32 %0, %1" : "+v"(w0), "+v"(w2));
        u32 w1 = pk[1], w3 = pk[3];
        asm volatile("v_permlane32_swap_b32 %0, %1" : "+v"(w1), "+v"(w3));
        u32 w4 = pk[4], w6 = pk[6];
        asm volatile("v_permlane32_swap_b32 %0, %1" : "+v"(w4), "+v"(w6));
        u32 w5 = pk[5], w7 = pk[7];
        asm volatile("v_permlane32_swap_b32 %0, %1" : "+v"(w5), "+v"(w7));
        short8 pf0, pf1;
        pf0[0] = (short)(w0 & 0xffff); pf0[1] = (short)(w0 >> 16);
        pf0[2] = (short)(w1 & 0xffff); pf0[3] = (short)(w1 >> 16);
        pf0[4] = (short)(w2 & 0xffff); pf0[5] = (short)(w2 >> 16);
        pf0[6] = (short)(w3 & 0xffff); pf0[7] = (short)(w3 >> 16);
        pf1[0] = (short)(w4 & 0xffff); pf1[1] = (short)(w4 >> 16);
        pf1[2] = (short)(w5 & 0xffff); pf1[3] = (short)(w5 >> 16);
        pf1[4] = (short)(w6 & 0xffff); pf1[5] = (short)(w6 >> 16);
        pf1[6] = (short)(w7 & 0xffff); pf1[7] = (short)(w7 >> 16);

        o0 = mfma32(vf[0], pf0, o0);
        o0 = mfma32(vf[1], pf1, o0);
        o1 = mfma32(vf[2], pf0, o1);
        o1 = mfma32(vf[3], pf1, o1);

#pragma unroll
        for (int ks = 0; ks < 4; ++ks) { qf[ks] = qn[ks]; vf[ks] = vn[ks]; }
    }

    // ---- partial store to LDS ----
#pragma unroll
    for (int q = 0; q < 8; ++q) {
        const int dp = (q & 1) + 4 * (q >> 1) + 2 * h;
        sO[wid][dp][l5]      = packbf(o0[2 * q], o0[2 * q + 1]);
        sO[wid][16 + dp][l5] = packbf(o1[2 * q], o1[2 * q + 1]);
    }
    if (h == 0) { sML[wid][0][l5] = m; sML[wid][1][l5] = l; }
    __syncthreads();

    // ---- 8-way merge ----
    float M = -1e30f;
#pragma unroll
    for (int p = 0; p < 8; ++p) M = fmaxf(M, sML[p][0][l5]);
    float L = 0.f;
    float av[4] = {};
#pragma unroll
    for (int p = 0; p < 8; ++p) {
        const float w = exp2f(sML[p][0][l5] - M);
        L += w * sML[p][1][l5];
#pragma unroll
        for (int dd2 = 0; dd2 < 2; ++dd2) {
            const u32 v = sO[p][wid * 4 + h * 2 + dd2][l5];
            av[2 * dd2]     += w * bf2f((unsigned short)(v & 0xffff));
            av[2 * dd2 + 1] += w * bf2f((unsigned short)(v >> 16));
        }
    }
    const float inv = 1.f / L;
    f32x4 r = { av[0] * inv, av[1] * inv, av[2] * inv, av[3] * inv };
    *(f32x4*)&out[((size_t)b * T + t0 + l5) * HD + wid * 8 + h * 4] = r;
}

extern "C" void kernel_launch(void* const* d_in, const int* in_sizes, int n_in,
                              void* d_out, int out_size, void* d_ws, size_t ws_size,
                              hipStream_t stream) {
    const float* x  = (const float*)d_in[0];
    const float* Wk = (const float*)d_in[1];
    const float* Wq = (const float*)d_in[2];
    const float* Wv = (const float*)d_in[3];
    float* out = (float*)d_out;

    short* kfrag = (short*)d_ws;                        // [512 tiles][4][64][8]
    short* qfrag = kfrag + (size_t)BATCH * T * HD;
    short* vfrag = qfrag + (size_t)BATCH * T * HD;
    short* wfrag = vfrag + (size_t)BATCH * T * HD;      // [12][32][64][8]

    wcvt_kernel<<<96, 256, 0, stream>>>(Wk, Wq, Wv, wfrag);
    proj_kernel<<<512, 256, 0, stream>>>(x, wfrag, kfrag, qfrag, vfrag);
    attn_kernel<<<512, 512, 0, stream>>>(kfrag, qfrag, vfrag, out);
}